// Round 4
// baseline (417.553 us; speedup 1.0000x reference)
//
#include <hip/hip_runtime.h>
#include <hip/hip_bf16.h>

// All float tensors (inputs AND outputs) are f32 (proven: bf16 reads -> NaN,
// f32 reads -> finite deterministic; error magnitude matched bf16-packed
// outputs being read as f32).

// ---------------- workspace layout (f32 words) ----------------
#define WS_CAT1   0        // [embedded(512), h0(1024)]
#define WS_COMB   1536     // [embedded(512), applied(1024), av(512)]
#define WS_PRE    3584     // 512
#define WS_ATTNW  4096     // 512
#define WS_X      4608     // 1024
#define WS_GATES  5632     // 4096
#define WS_HNEW   9728     // 1024

// output layout (f32): logits[50257], h_new[1024], c_new[1024], attn_w[512]
#define OUT_H     50257
#define OUT_C     51281
#define OUT_AW    52305

__device__ __forceinline__ float wave_partial_dot(const float* __restrict__ Wrow,
                                                  const float* __restrict__ x,
                                                  int cols) {
  int lane = threadIdx.x & 63;
  float acc = 0.f;
  for (int c = lane * 4; c < cols; c += 256) {
    float4 w  = *reinterpret_cast<const float4*>(Wrow + c);
    float4 xv = *reinterpret_cast<const float4*>(x + c);
    acc += w.x * xv.x + w.y * xv.y + w.z * xv.z + w.w * xv.w;
  }
  return acc;
}

__device__ __forceinline__ float wave_reduce(float acc) {
#pragma unroll
  for (int off = 32; off > 0; off >>= 1) acc += __shfl_xor(acc, off, 64);
  return acc;
}

// prep: gather embedding row, stage concat vectors in ws
__global__ __launch_bounds__(1024) void prep_k(const int* __restrict__ word,
                                               const float* __restrict__ emb_table,
                                               const float* __restrict__ h0,
                                               const float* __restrict__ av,
                                               float* __restrict__ ws) {
  int t = threadIdx.x;
  int w = word[0];
  if (t < 512) {
    float e = emb_table[(size_t)w * 512 + t];
    ws[WS_CAT1 + t] = e;                 // cat1 embedded
    ws[WS_COMB + t] = e;                 // comb embedded
    ws[WS_COMB + 1536 + t] = av[t];      // comb av_emb
  }
  ws[WS_CAT1 + 512 + t] = h0[t];         // h0
}

template <int COLS, bool RELU>
__global__ __launch_bounds__(256) void matvec_k(const float* __restrict__ W,
                                                const float* __restrict__ bias,
                                                const float* __restrict__ x,
                                                float* __restrict__ y,
                                                int rows) {
  int row = blockIdx.x * 4 + (threadIdx.x >> 6);
  if (row >= rows) return;
  float acc = wave_partial_dot(W + (size_t)row * COLS, x, COLS);
  acc = wave_reduce(acc);
  if ((threadIdx.x & 63) == 0) {
    acc += bias[row];
    if (RELU) acc = fmaxf(acc, 0.f);
    y[row] = acc;
  }
}

__global__ __launch_bounds__(512) void softmax_k(const float* __restrict__ pre,
                                                 float* __restrict__ wout,
                                                 float* __restrict__ out_w) {
  __shared__ float red[8];
  __shared__ float stat[2];
  int t = threadIdx.x;
  int lane = t & 63, wid = t >> 6;
  float v = pre[t];
  float m = v;
#pragma unroll
  for (int off = 32; off > 0; off >>= 1) m = fmaxf(m, __shfl_xor(m, off, 64));
  if (lane == 0) red[wid] = m;
  __syncthreads();
  if (t == 0) {
    float mm = red[0];
    for (int i = 1; i < 8; i++) mm = fmaxf(mm, red[i]);
    stat[0] = mm;
  }
  __syncthreads();
  float e = expf(v - stat[0]);
  float s = e;
#pragma unroll
  for (int off = 32; off > 0; off >>= 1) s += __shfl_xor(s, off, 64);
  if (lane == 0) red[wid] = s;
  __syncthreads();
  if (t == 0) {
    float ss = 0.f;
    for (int i = 0; i < 8; i++) ss += red[i];
    stat[1] = ss;
  }
  __syncthreads();
  float w = e / stat[1];
  wout[t] = w;
  out_w[t] = w;
}

// attn_applied[j] = sum_l w[l] * enc[l][j]   (enc row-major [512,1024] f32)
__global__ __launch_bounds__(256) void attn_apply_k(const float* __restrict__ w,
                                                    const float* __restrict__ enc,
                                                    float* __restrict__ out) {
  int j = blockIdx.x * 256 + threadIdx.x;  // grid 4 -> 1024
  float a0 = 0.f, a1 = 0.f, a2 = 0.f, a3 = 0.f;
  for (int l = 0; l < 512; l += 4) {
    a0 += w[l + 0] * enc[(size_t)(l + 0) * 1024 + j];
    a1 += w[l + 1] * enc[(size_t)(l + 1) * 1024 + j];
    a2 += w[l + 2] * enc[(size_t)(l + 2) * 1024 + j];
    a3 += w[l + 3] * enc[(size_t)(l + 3) * 1024 + j];
  }
  out[j] = (a0 + a1) + (a2 + a3);
}

// gates[row] = W_ih[row]·x + b_ih[row] + W_hh[row]·h0 + b_hh[row]
__global__ __launch_bounds__(256) void gates_k(const float* __restrict__ Wih,
                                               const float* __restrict__ Whh,
                                               const float* __restrict__ bih,
                                               const float* __restrict__ bhh,
                                               const float* __restrict__ x,
                                               const float* __restrict__ h,
                                               float* __restrict__ g) {
  int row = blockIdx.x * 4 + (threadIdx.x >> 6);  // 4096 rows, grid 1024
  float acc = wave_partial_dot(Wih + (size_t)row * 1024, x, 1024) +
              wave_partial_dot(Whh + (size_t)row * 1024, h, 1024);
  acc = wave_reduce(acc);
  if ((threadIdx.x & 63) == 0) g[row] = acc + bih[row] + bhh[row];
}

__global__ __launch_bounds__(1024) void lstm_k(const float* __restrict__ g,
                                               const float* __restrict__ c0,
                                               float* __restrict__ hnew_f,
                                               float* __restrict__ out_h,
                                               float* __restrict__ out_c) {
  int t = threadIdx.x;
  float gi = g[t], gf = g[1024 + t], gg = g[2048 + t], go = g[3072 + t];
  float i = 1.f / (1.f + expf(-gi));
  float f = 1.f / (1.f + expf(-gf));
  float gt = tanhf(gg);
  float o = 1.f / (1.f + expf(-go));
  float cn = f * c0[t] + i * gt;
  float hn = o * tanhf(cn);
  hnew_f[t] = hn;
  out_h[t] = hn;
  out_c[t] = cn;
}

template <int COLS>
__global__ __launch_bounds__(256) void matvec_out_k(const float* __restrict__ W,
                                                    const float* __restrict__ bias,
                                                    const float* __restrict__ x,
                                                    float* __restrict__ y,
                                                    int rows) {
  int row = blockIdx.x * 4 + (threadIdx.x >> 6);
  if (row >= rows) return;
  float acc = wave_partial_dot(W + (size_t)row * COLS, x, COLS);
  acc = wave_reduce(acc);
  if ((threadIdx.x & 63) == 0) {
    y[row] = acc + bias[row];
  }
}

extern "C" void kernel_launch(void* const* d_in, const int* in_sizes, int n_in,
                              void* d_out, int out_size, void* d_ws, size_t ws_size,
                              hipStream_t stream) {
  const int*   word   = (const int*)  d_in[0];
  // d_in[1] = enc_seq_len (==1 -> reference row-mask is a no-op)
  const float* av     = (const float*)d_in[2];
  const float* h0     = (const float*)d_in[3];
  const float* c0     = (const float*)d_in[4];
  const float* enc    = (const float*)d_in[5];
  const float* emb    = (const float*)d_in[6];
  const float* attn_W = (const float*)d_in[7];
  const float* attn_b = (const float*)d_in[8];
  const float* comb_W = (const float*)d_in[9];
  const float* comb_b = (const float*)d_in[10];
  const float* W_ih   = (const float*)d_in[11];
  const float* W_hh   = (const float*)d_in[12];
  const float* b_ih   = (const float*)d_in[13];
  const float* b_hh   = (const float*)d_in[14];
  const float* out_W  = (const float*)d_in[15];
  const float* out_b  = (const float*)d_in[16];

  float* ws  = (float*)d_ws;
  float* out = (float*)d_out;

  prep_k<<<1, 1024, 0, stream>>>(word, emb, h0, av, ws);
  matvec_k<1536, false><<<128, 256, 0, stream>>>(attn_W, attn_b,
      ws + WS_CAT1, ws + WS_PRE, 512);
  softmax_k<<<1, 512, 0, stream>>>(ws + WS_PRE, ws + WS_ATTNW, out + OUT_AW);
  attn_apply_k<<<4, 256, 0, stream>>>(ws + WS_ATTNW, enc, ws + WS_COMB + 512);
  matvec_k<2048, true><<<256, 256, 0, stream>>>(comb_W, comb_b,
      ws + WS_COMB, ws + WS_X, 1024);
  gates_k<<<1024, 256, 0, stream>>>(W_ih, W_hh, b_ih, b_hh,
      ws + WS_X, ws + WS_CAT1 + 512, ws + WS_GATES);
  lstm_k<<<1, 1024, 0, stream>>>(ws + WS_GATES, c0,
      ws + WS_HNEW, out + OUT_H, out + OUT_C);
  matvec_out_k<1024><<<(50257 + 3) / 4, 256, 0, stream>>>(out_W, out_b,
      ws + WS_HNEW, out, 50257);
}

// Round 5
// 395.592 us; speedup vs baseline: 1.0555x; 1.0555x over previous
//
#include <hip/hip_runtime.h>

// All float tensors (inputs AND outputs) are f32 (established rounds 0-4).
// H=1024, E=512, A=512, L=512, V=50257. enc_seq_len==1 -> mask is a no-op.

#define V 50257

// ---------------- workspace layout (f32 words) ----------------
#define WS_PRE    0      // attn_pre (512)
#define WS_ATTNW  512    // softmax weights f32 (512)
#define WS_APPL   1024   // attn_applied (1024)
#define WS_X      2048   // combine+relu output (1024)

// output layout (f32): logits[50257], h_new[1024], c_new[1024], attn_w[512]
#define OUT_H     50257
#define OUT_C     51281
#define OUT_AW    52305

__device__ __forceinline__ float4 ld4(const float* p) {
  return *reinterpret_cast<const float4*>(p);
}
__device__ __forceinline__ float dot4(float4 a, float4 b) {
  return a.x * b.x + a.y * b.y + a.z * b.z + a.w * b.w;
}
__device__ __forceinline__ float wave_reduce(float a) {
#pragma unroll
  for (int off = 32; off > 0; off >>= 1) a += __shfl_xor(a, off, 64);
  return a;
}
__device__ __forceinline__ float sigf(float v) {
  return 1.f / (1.f + expf(-v));
}

// K1: attn_pre[row] = attn_W[row]·[emb(word), h0] + attn_b[row]  (512 rows)
__global__ __launch_bounds__(256) void attn_mv_k(const float* __restrict__ attn_W,
                                                 const float* __restrict__ attn_b,
                                                 const float* __restrict__ emb,
                                                 const int* __restrict__ word,
                                                 const float* __restrict__ h0,
                                                 float* __restrict__ pre) {
  int row = blockIdx.x * 4 + (threadIdx.x >> 6);
  int lane = threadIdx.x & 63;
  const float* Wr = attn_W + (size_t)row * 1536;
  const float* er = emb + (size_t)word[0] * 512;
  float acc = 0.f;
#pragma unroll
  for (int k = 0; k < 2; k++) {           // cols 0..511: embedded
    int c = lane * 4 + k * 256;
    acc += dot4(ld4(Wr + c), ld4(er + c));
  }
#pragma unroll
  for (int k = 2; k < 6; k++) {           // cols 512..1535: h0
    int c = lane * 4 + k * 256;
    acc += dot4(ld4(Wr + c), ld4(h0 + c - 512));
  }
  acc = wave_reduce(acc);
  if (lane == 0) pre[row] = acc + attn_b[row];
}

// K2: softmax over 512; writes f32 weights to ws + out; zeroes applied buffer
__global__ __launch_bounds__(512) void softmax_k(const float* __restrict__ pre,
                                                 float* __restrict__ wout,
                                                 float* __restrict__ out_w,
                                                 float* __restrict__ applied) {
  __shared__ float red[8];
  __shared__ float stat[2];
  int t = threadIdx.x;
  int lane = t & 63, wid = t >> 6;
  applied[t] = 0.f;                        // zero 1024-wide applied buffer
  applied[512 + t] = 0.f;
  float v = pre[t];
  float m = v;
#pragma unroll
  for (int off = 32; off > 0; off >>= 1) m = fmaxf(m, __shfl_xor(m, off, 64));
  if (lane == 0) red[wid] = m;
  __syncthreads();
  if (t == 0) {
    float mm = red[0];
    for (int i = 1; i < 8; i++) mm = fmaxf(mm, red[i]);
    stat[0] = mm;
  }
  __syncthreads();
  float e = expf(v - stat[0]);
  float s = e;
#pragma unroll
  for (int off = 32; off > 0; off >>= 1) s += __shfl_xor(s, off, 64);
  if (lane == 0) red[wid] = s;
  __syncthreads();
  if (t == 0) {
    float ss = 0.f;
    for (int i = 0; i < 8; i++) ss += red[i];
    stat[1] = ss;
  }
  __syncthreads();
  float w = e / stat[1];
  wout[t] = w;
  out_w[t] = w;
}

// K3: applied[j] += sum_{l in chunk} w[l]*enc[l][j]; 32 blocks (8 l-chunks x 4 j-blocks)
__global__ __launch_bounds__(256) void attn_apply_k(const float* __restrict__ w,
                                                    const float* __restrict__ enc,
                                                    float* __restrict__ applied) {
  int jb = blockIdx.x & 3, lb = blockIdx.x >> 2;
  int j = jb * 256 + threadIdx.x;
  int l0 = lb * 64;
  float acc = 0.f;
#pragma unroll 4
  for (int l = l0; l < l0 + 64; l++) acc += w[l] * enc[(size_t)l * 1024 + j];
  atomicAdd(applied + j, acc);
}

// K4: x[row] = relu(comb_W[row]·[emb, applied, av] + comb_b[row])  (1024 rows)
__global__ __launch_bounds__(256) void comb_mv_k(const float* __restrict__ comb_W,
                                                 const float* __restrict__ comb_b,
                                                 const float* __restrict__ emb,
                                                 const int* __restrict__ word,
                                                 const float* __restrict__ applied,
                                                 const float* __restrict__ av,
                                                 float* __restrict__ x) {
  int row = blockIdx.x * 4 + (threadIdx.x >> 6);
  int lane = threadIdx.x & 63;
  const float* Wr = comb_W + (size_t)row * 2048;
  const float* er = emb + (size_t)word[0] * 512;
  float acc = 0.f;
#pragma unroll
  for (int k = 0; k < 2; k++) {           // cols 0..511: embedded
    int c = lane * 4 + k * 256;
    acc += dot4(ld4(Wr + c), ld4(er + c));
  }
#pragma unroll
  for (int k = 2; k < 6; k++) {           // cols 512..1535: applied
    int c = lane * 4 + k * 256;
    acc += dot4(ld4(Wr + c), ld4(applied + c - 512));
  }
#pragma unroll
  for (int k = 6; k < 8; k++) {           // cols 1536..2047: av_emb
    int c = lane * 4 + k * 256;
    acc += dot4(ld4(Wr + c), ld4(av + c - 1536));
  }
  acc = wave_reduce(acc);
  if (lane == 0) x[row] = fmaxf(acc + comb_b[row], 0.f);
}

// K5: fused gates+LSTM. Block t: wave w computes gate row w*1024+t; thread 0
// applies pointwise LSTM for index t. 1024 blocks.
__global__ __launch_bounds__(256) void gates_lstm_k(const float* __restrict__ Wih,
                                                    const float* __restrict__ Whh,
                                                    const float* __restrict__ bih,
                                                    const float* __restrict__ bhh,
                                                    const float* __restrict__ x,
                                                    const float* __restrict__ h0,
                                                    const float* __restrict__ c0,
                                                    float* __restrict__ out_h,
                                                    float* __restrict__ out_c) {
  __shared__ float gsh[4];
  int t = blockIdx.x;
  int wv = threadIdx.x >> 6, lane = threadIdx.x & 63;
  size_t r = (size_t)wv * 1024 + t;       // wv: 0=i 1=f 2=g 3=o (torch order)
  const float* Wi = Wih + r * 1024;
  const float* Wh = Whh + r * 1024;
  float acc = 0.f;
#pragma unroll
  for (int k = 0; k < 4; k++) {
    int c = lane * 4 + k * 256;
    acc += dot4(ld4(Wi + c), ld4(x + c));
    acc += dot4(ld4(Wh + c), ld4(h0 + c));
  }
  acc = wave_reduce(acc);
  if (lane == 0) gsh[wv] = acc + bih[r] + bhh[r];
  __syncthreads();
  if (threadIdx.x == 0) {
    float gi = sigf(gsh[0]);
    float gf = sigf(gsh[1]);
    float gg = tanhf(gsh[2]);
    float go = sigf(gsh[3]);
    float cn = gf * c0[t] + gi * gg;
    float hn = go * tanhf(cn);
    out_h[t] = hn;
    out_c[t] = cn;
  }
}

// K6: logits[row] = out_W[row]·h_new + out_b[row]; 2 rows/wave, 8 rows/block
__global__ __launch_bounds__(256) void logits_mv_k(const float* __restrict__ W,
                                                   const float* __restrict__ bias,
                                                   const float* __restrict__ x,
                                                   float* __restrict__ y) {
  int wv = threadIdx.x >> 6, lane = threadIdx.x & 63;
  int r0 = blockIdx.x * 8 + wv * 2;
  if (r0 >= V) return;
  bool has1 = (r0 + 1) < V;
  const float* W0 = W + (size_t)r0 * 1024;
  float a0 = 0.f, a1 = 0.f;
#pragma unroll
  for (int k = 0; k < 4; k++) {
    int c = lane * 4 + k * 256;
    float4 xv = ld4(x + c);
    a0 += dot4(ld4(W0 + c), xv);
    if (has1) a1 += dot4(ld4(W0 + 1024 + c), xv);
  }
  a0 = wave_reduce(a0);
  a1 = wave_reduce(a1);
  if (lane == 0) {
    y[r0] = a0 + bias[r0];
    if (has1) y[r0 + 1] = a1 + bias[r0 + 1];
  }
}

extern "C" void kernel_launch(void* const* d_in, const int* in_sizes, int n_in,
                              void* d_out, int out_size, void* d_ws, size_t ws_size,
                              hipStream_t stream) {
  const int*   word   = (const int*)  d_in[0];
  // d_in[1] = enc_seq_len (==1 -> reference row-mask is a no-op)
  const float* av     = (const float*)d_in[2];
  const float* h0     = (const float*)d_in[3];
  const float* c0     = (const float*)d_in[4];
  const float* enc    = (const float*)d_in[5];
  const float* emb    = (const float*)d_in[6];
  const float* attn_W = (const float*)d_in[7];
  const float* attn_b = (const float*)d_in[8];
  const float* comb_W = (const float*)d_in[9];
  const float* comb_b = (const float*)d_in[10];
  const float* W_ih   = (const float*)d_in[11];
  const float* W_hh   = (const float*)d_in[12];
  const float* b_ih   = (const float*)d_in[13];
  const float* b_hh   = (const float*)d_in[14];
  const float* out_W  = (const float*)d_in[15];
  const float* out_b  = (const float*)d_in[16];

  float* ws  = (float*)d_ws;
  float* out = (float*)d_out;

  attn_mv_k<<<128, 256, 0, stream>>>(attn_W, attn_b, emb, word, h0, ws + WS_PRE);
  softmax_k<<<1, 512, 0, stream>>>(ws + WS_PRE, ws + WS_ATTNW, out + OUT_AW,
                                   ws + WS_APPL);
  attn_apply_k<<<32, 256, 0, stream>>>(ws + WS_ATTNW, enc, ws + WS_APPL);
  comb_mv_k<<<256, 256, 0, stream>>>(comb_W, comb_b, emb, word, ws + WS_APPL,
                                     av, ws + WS_X);
  gates_lstm_k<<<1024, 256, 0, stream>>>(W_ih, W_hh, b_ih, b_hh, ws + WS_X,
                                         h0, c0, out + OUT_H, out + OUT_C);
  logits_mv_k<<<(V + 7) / 8, 256, 0, stream>>>(out_W, out_b, out + OUT_H, out);
}